// Round 4
// baseline (368.245 us; speedup 1.0000x reference)
//
#include <hip/hip_runtime.h>

// Sizes (fixed by the problem)
#define BB 4
#define CC 256
#define HH 128
#define WW 128
#define HP 64          // pooled H, W
#define NP 4096        // HP*HP tokens per batch

typedef __attribute__((ext_vector_type(4))) float f32x4;
typedef __attribute__((ext_vector_type(8))) short bf16x8;   // 8 bf16 in 4 VGPRs

// float -> bf16 bits, round-to-nearest-even (finite inputs only)
static __device__ __forceinline__ unsigned short f2bf(float f) {
    unsigned int u = __float_as_uint(f);
    u = (u + 0x7FFFu + ((u >> 16) & 1u)) >> 16;
    return (unsigned short)u;
}

// ---------------------------------------------------------------------------
// K1: 2x2 average pool. x[b][c][128][128] -> xp[b][c][64*64]
// ---------------------------------------------------------------------------
__global__ __launch_bounds__(256) void pool_kernel(const float* __restrict__ x,
                                                   float* __restrict__ xp) {
    int tid = blockIdx.x * 256 + threadIdx.x;      // B*C*NP threads
    int wp = tid & 63;
    int hp = (tid >> 6) & 63;
    int bc = tid >> 12;
    const float* src = x + (size_t)bc * (HH * WW) + (2 * hp) * WW + 2 * wp;
    float2 a = *(const float2*)(src);
    float2 b = *(const float2*)(src + WW);
    xp[tid] = 0.25f * (a.x + a.y + b.x + b.y);
}

// ---------------------------------------------------------------------------
// K2: fused QKV projection GEMM (fp32 math), bf16 outputs in two layouts:
//   qk[b][n][64]  : o 0..31 = q, 32..63 = k   (token-major, for QK^T frags)
//   vt[b][c][n]   : c 0..255                  (channel-major, for PV B frags)
// ---------------------------------------------------------------------------
__global__ __launch_bounds__(256) void proj_kernel(const float* __restrict__ xp,
    const float* __restrict__ wq, const float* __restrict__ bq,
    const float* __restrict__ wk, const float* __restrict__ bk,
    const float* __restrict__ wv, const float* __restrict__ bv,
    unsigned short* __restrict__ qk, unsigned short* __restrict__ vt) {
    __shared__ float lx[32][64];    // [c][n]
    __shared__ float lwT[32][64];   // [c][o]
    int t = threadIdx.x;
    int ot = blockIdx.x % 5;
    int nt = (blockIdx.x / 5) & 63;
    int b  = blockIdx.x / 320;

    float acc[4][4];
    #pragma unroll
    for (int i = 0; i < 4; i++)
        #pragma unroll
        for (int j = 0; j < 4; j++) acc[i][j] = 0.f;

    int n0 = (t & 15) * 4;
    int o0 = (t >> 4) * 4;

    int o_l = t >> 2;               // 0..63 weight row
    int og  = ot * 64 + o_l;
    const float* wrow;
    if (og < 32)      wrow = wq + og * CC;
    else if (og < 64) wrow = wk + (og - 32) * CC;
    else              wrow = wv + (og - 64) * CC;
    int c8 = (t & 3) * 8;

    const float* xbase = xp + (size_t)b * CC * NP + nt * 64;
    int cl = t >> 3;                // 0..31
    int nl = (t & 7) * 8;

    for (int c0 = 0; c0 < 256; c0 += 32) {
        const float* xg = xbase + (size_t)(c0 + cl) * NP + nl;
        float4 v0 = *(const float4*)(xg);
        float4 v1 = *(const float4*)(xg + 4);
        float4 w0 = *(const float4*)(wrow + c0 + c8);
        float4 w1 = *(const float4*)(wrow + c0 + c8 + 4);
        __syncthreads();
        *(float4*)&lx[cl][nl]     = v0;
        *(float4*)&lx[cl][nl + 4] = v1;
        lwT[c8 + 0][o_l] = w0.x; lwT[c8 + 1][o_l] = w0.y;
        lwT[c8 + 2][o_l] = w0.z; lwT[c8 + 3][o_l] = w0.w;
        lwT[c8 + 4][o_l] = w1.x; lwT[c8 + 5][o_l] = w1.y;
        lwT[c8 + 6][o_l] = w1.z; lwT[c8 + 7][o_l] = w1.w;
        __syncthreads();
        #pragma unroll
        for (int cc = 0; cc < 32; cc += 4) {
            float4 xv[4], wv4[4];
            #pragma unroll
            for (int ci = 0; ci < 4; ci++) {
                xv[ci]  = *(const float4*)&lx[cc + ci][n0];
                wv4[ci] = *(const float4*)&lwT[cc + ci][o0];
            }
            #pragma unroll
            for (int ci = 0; ci < 4; ci++) {
                float xn[4] = {xv[ci].x, xv[ci].y, xv[ci].z, xv[ci].w};
                float wo[4] = {wv4[ci].x, wv4[ci].y, wv4[ci].z, wv4[ci].w};
                #pragma unroll
                for (int ni = 0; ni < 4; ni++)
                    #pragma unroll
                    for (int oi = 0; oi < 4; oi++)
                        acc[ni][oi] += xn[ni] * wo[oi];
            }
        }
    }

    float bias[4];
    #pragma unroll
    for (int oi = 0; oi < 4; oi++) {
        int o = ot * 64 + o0 + oi;
        bias[oi] = (o < 32) ? bq[o] : (o < 64) ? bk[o - 32] : bv[o - 64];
    }

    if (ot == 0) {
        #pragma unroll
        for (int ni = 0; ni < 4; ni++) {
            ushort4 r;
            r.x = f2bf(acc[ni][0] + bias[0]);
            r.y = f2bf(acc[ni][1] + bias[1]);
            r.z = f2bf(acc[ni][2] + bias[2]);
            r.w = f2bf(acc[ni][3] + bias[3]);
            int n = nt * 64 + n0 + ni;
            *(ushort4*)(qk + ((size_t)b * NP + n) * 64 + o0) = r;
        }
    } else {
        #pragma unroll
        for (int oi = 0; oi < 4; oi++) {
            int c = ot * 64 + o0 + oi - 64;
            ushort4 r;
            r.x = f2bf(acc[0][oi] + bias[oi]);
            r.y = f2bf(acc[1][oi] + bias[oi]);
            r.z = f2bf(acc[2][oi] + bias[oi]);
            r.w = f2bf(acc[3][oi] + bias[oi]);
            *(ushort4*)(vt + ((size_t)b * CC + c) * NP + nt * 64 + n0) = r;
        }
    }
}

// ---------------------------------------------------------------------------
// K3: MFMA flash attention, split-K x4 AND channel-split x2.
// Block j: batch b=(j&7)>>1, channel half h=j&1, q-tile qt=j>>3.
//   -> batch b's blocks land only on XCDs {2b,2b+1} (blockIdx round-robins
//      XCDs), and each XCD sees only one channel half: per-XCD working set
//      = qk (2MB) + V-half (1MB) = 3MB < 4MB L2. No thrash.
// Wave w handles key chunks [w*16, w*16+16) for 16 q-rows x 128 channels
// (acc = 8 f32x4 = 32 regs -> total <=128 -> 4 waves/SIMD via launch_bounds).
// QK^T + softmax are computed redundantly per channel half (cheap).
// States merged elementwise through LDS at the end; wave 0 writes.
//
// mfma_f32_16x16x32_bf16 layouts (m89-verified):
//   A: row = lane&15, k = (lane>>4)*8 + e
//   B: col = lane&15, k = (lane>>4)*8 + e
//   D: col = lane&15, row = (lane>>4)*4 + reg
// ---------------------------------------------------------------------------
__global__ __launch_bounds__(256, 4) void flashm_kernel(const unsigned short* __restrict__ qk,
                                                        const unsigned short* __restrict__ vt,
                                                        float* __restrict__ att) {
    __shared__ char  p_lds[4][2048];  // per wave: P tile 16 rows x 64 keys bf16, XOR-swizzled
    __shared__ float cacc[64][36];    // combine: one wave's acc (64 lanes x 32 f32), padded
    __shared__ float cml[64][8];      // combine: m[4], l[4] per lane
    int t    = threadIdx.x;
    int lane = t & 63;
    int w    = t >> 6;
    int j    = blockIdx.x;
    int b    = (j & 7) >> 1;          // batch -> XCD pair
    int h    = j & 1;                 // channel half -> one XCD of the pair
    int qt   = j >> 3;                // 0..255 q-tile

    const unsigned short* qkb = qk + (size_t)b * NP * 64;
    const unsigned short* vtb = vt + ((size_t)b * CC + h * 128) * NP;
    char* pl = p_lds[w];

    int lr = lane & 15;
    int lg = lane >> 4;

    // Q A-fragment: row qt*16+lr, channels lg*8..+7 (held for the whole kernel)
    bf16x8 qf = *(const bf16x8*)(qkb + ((size_t)(qt * 16 + lr)) * 64 + lg * 8);

    f32x4 acc[8];
    #pragma unroll
    for (int i = 0; i < 8; i++) acc[i] = (f32x4){0.f, 0.f, 0.f, 0.f};
    float mrun[4] = {-3.0e38f, -3.0e38f, -3.0e38f, -3.0e38f};
    float lrun[4] = {0.f, 0.f, 0.f, 0.f};

    for (int kc = w * 16; kc < w * 16 + 16; ++kc) {
        int kbase = kc * 64;

        // ---- QK^T: 4 MFMA -> S[16 q][64 keys]
        f32x4 s[4];
        #pragma unroll
        for (int kt = 0; kt < 4; kt++) {
            bf16x8 kf = *(const bf16x8*)(qkb + ((size_t)(kbase + kt * 16 + lr)) * 64 + 32 + lg * 8);
            s[kt] = __builtin_amdgcn_mfma_f32_16x16x32_bf16(qf, kf,
                        (f32x4){0.f, 0.f, 0.f, 0.f}, 0, 0, 0);
        }

        // ---- chunk max (rows live in 16-lane groups; reduce via shfl_xor)
        float mx[4];
        #pragma unroll
        for (int r = 0; r < 4; r++)
            mx[r] = fmaxf(fmaxf(s[0][r], s[1][r]), fmaxf(s[2][r], s[3][r]));
        #pragma unroll
        for (int d = 1; d < 16; d <<= 1)
            #pragma unroll
            for (int r = 0; r < 4; r++)
                mx[r] = fmaxf(mx[r], __shfl_xor(mx[r], d, 64));

        // ---- defer-max (T13): only rescale when the max grew by > 8
        float need = mx[0] - mrun[0];
        #pragma unroll
        for (int r = 1; r < 4; r++) need = fmaxf(need, mx[r] - mrun[r]);
        if (!__all(need <= 8.0f)) {
            float sc[4];
            #pragma unroll
            for (int r = 0; r < 4; r++) {
                float mnew = fmaxf(mrun[r], mx[r]);
                sc[r]   = __expf(mrun[r] - mnew);
                mrun[r] = mnew;
                lrun[r] *= sc[r];
            }
            #pragma unroll
            for (int ct = 0; ct < 8; ct++)
                #pragma unroll
                for (int r = 0; r < 4; r++) acc[ct][r] *= sc[r];
        }

        // ---- P = exp(S - m), P-sum, P -> LDS (bf16, XOR-swizzled)
        float ps[4] = {0.f, 0.f, 0.f, 0.f};
        #pragma unroll
        for (int kt = 0; kt < 4; kt++) {
            #pragma unroll
            for (int r = 0; r < 4; r++) {
                float p = __expf(s[kt][r] - mrun[r]);
                ps[r] += p;
                int row = lg * 4 + r;
                int key = kt * 16 + lr;
                int off = (row * 128 + key * 2) ^ ((row & 7) << 4);
                *(unsigned short*)(pl + off) = f2bf(p);
            }
        }
        #pragma unroll
        for (int d = 1; d < 16; d <<= 1)
            #pragma unroll
            for (int r = 0; r < 4; r++)
                ps[r] += __shfl_xor(ps[r], d, 64);
        #pragma unroll
        for (int r = 0; r < 4; r++) lrun[r] += ps[r];

        // make this wave's P writes visible to its own cross-lane reads
        asm volatile("s_waitcnt lgkmcnt(0)" ::: "memory");
        __builtin_amdgcn_sched_barrier(0);

        // ---- PV: 2 K-steps x 8 channel tiles = 16 MFMA
        #pragma unroll
        for (int kt2 = 0; kt2 < 2; kt2++) {
            int roff = (lr * 128 + (kt2 * 32 + lg * 8) * 2) ^ ((lr & 7) << 4);
            bf16x8 pf = *(const bf16x8*)(pl + roff);
            const unsigned short* vb = vtb + kbase + kt2 * 32 + lg * 8;
            #pragma unroll
            for (int ct = 0; ct < 8; ct++) {
                bf16x8 vf = *(const bf16x8*)(vb + (size_t)(ct * 16 + lr) * NP);
                acc[ct] = __builtin_amdgcn_mfma_f32_16x16x32_bf16(pf, vf, acc[ct], 0, 0, 0);
            }
        }
    }

    // ---- split-K combine: waves 3,2,1 hand state to wave 0 (elementwise per lane)
    for (int s = 3; s >= 1; --s) {
        if (w == s) {
            #pragma unroll
            for (int ct = 0; ct < 8; ct++) *(f32x4*)&cacc[lane][ct * 4] = acc[ct];
            #pragma unroll
            for (int r = 0; r < 4; r++) { cml[lane][r] = mrun[r]; cml[lane][4 + r] = lrun[r]; }
        }
        __syncthreads();
        if (w == 0) {
            float e0[4], e1[4];
            #pragma unroll
            for (int r = 0; r < 4; r++) {
                float mo = cml[lane][r];
                float lo = cml[lane][4 + r];
                float mn = fmaxf(mrun[r], mo);
                e0[r] = __expf(mrun[r] - mn);
                e1[r] = __expf(mo - mn);
                mrun[r] = mn;
                lrun[r] = lrun[r] * e0[r] + lo * e1[r];
            }
            #pragma unroll
            for (int ct = 0; ct < 8; ct++) {
                f32x4 o = *(const f32x4*)&cacc[lane][ct * 4];
                #pragma unroll
                for (int r = 0; r < 4; r++)
                    acc[ct][r] = acc[ct][r] * e0[r] + o[r] * e1[r];
            }
        }
        __syncthreads();
    }

    if (w == 0) {
        float inv[4];
        #pragma unroll
        for (int r = 0; r < 4; r++) inv[r] = 1.0f / lrun[r];
        #pragma unroll
        for (int ct = 0; ct < 8; ct++) {
            float4 o;
            o.x = acc[ct][0] * inv[0];
            o.y = acc[ct][1] * inv[1];
            o.z = acc[ct][2] * inv[2];
            o.w = acc[ct][3] * inv[3];
            int c = h * 128 + ct * 16 + lr;
            *(float4*)(att + ((size_t)b * CC + c) * NP + qt * 16 + lg * 4) = o;
        }
    }
}

// ---------------------------------------------------------------------------
// K4: bilinear x2 upsample (half-pixel, edge clamp) + gamma * up + x
// ---------------------------------------------------------------------------
__global__ __launch_bounds__(256) void upsample_kernel(const float* __restrict__ att,
                                                       const float* __restrict__ x,
                                                       const float* __restrict__ gamma,
                                                       float* __restrict__ out) {
    int tid = blockIdx.x * 256 + threadIdx.x;    // B*C*H*W
    int w = tid & 127;
    int h = (tid >> 7) & 127;
    int bc = tid >> 14;
    float g = gamma[0];
    float sh = 0.5f * h - 0.25f;
    float sw = 0.5f * w - 0.25f;
    float fhf = floorf(sh), fwf = floorf(sw);
    float th = sh - fhf, tw = sw - fwf;
    int ih = (int)fhf, iw = (int)fwf;
    int ih0 = ih < 0 ? 0 : ih;
    int ih1 = ih + 1 > 63 ? 63 : ih + 1;
    int iw0 = iw < 0 ? 0 : iw;
    int iw1 = iw + 1 > 63 ? 63 : iw + 1;
    const float* a = att + (size_t)bc * NP;
    float v00 = a[ih0 * 64 + iw0], v01 = a[ih0 * 64 + iw1];
    float v10 = a[ih1 * 64 + iw0], v11 = a[ih1 * 64 + iw1];
    float top = v00 + tw * (v01 - v00);
    float bot = v10 + tw * (v11 - v10);
    float up  = top + th * (bot - top);
    out[tid] = g * up + x[tid];
}

// ---------------------------------------------------------------------------
extern "C" void kernel_launch(void* const* d_in, const int* in_sizes, int n_in,
                              void* d_out, int out_size, void* d_ws, size_t ws_size,
                              hipStream_t stream) {
    (void)in_sizes; (void)n_in; (void)out_size; (void)ws_size;
    const float* x     = (const float*)d_in[0];
    const float* wq    = (const float*)d_in[1];
    const float* bq    = (const float*)d_in[2];
    const float* wk    = (const float*)d_in[3];
    const float* bk    = (const float*)d_in[4];
    const float* wv    = (const float*)d_in[5];
    const float* bv    = (const float*)d_in[6];
    const float* gamma = (const float*)d_in[7];
    float* out = (float*)d_out;
    float* ws  = (float*)d_ws;

    float*          xp  = ws;                                  // 4,194,304 f32 (16 MB)
    unsigned short* qkb = (unsigned short*)(ws + 4194304);     // 4*4096*64  bf16 (2 MB)
    unsigned short* vtb = qkb + 1048576;                       // 4*256*4096 bf16 (8 MB)
    float*          att = (float*)(vtb + 4194304);             // 4,194,304 f32 (16 MB)

    pool_kernel<<<16384, 256, 0, stream>>>(x, xp);
    proj_kernel<<<1280, 256, 0, stream>>>(xp, wq, bq, wk, bk, wv, bv, qkb, vtb);
    flashm_kernel<<<2048, 256, 0, stream>>>(qkb, vtb, att);
    upsample_kernel<<<65536, 256, 0, stream>>>(att, x, gamma, out);
}

// Round 5
// 234.291 us; speedup vs baseline: 1.5717x; 1.5717x over previous
//
#include <hip/hip_runtime.h>

// Sizes (fixed by the problem)
#define BB 4
#define CC 256
#define HH 128
#define WW 128
#define HP 64          // pooled H, W
#define NP 4096        // HP*HP tokens per batch

typedef __attribute__((ext_vector_type(4)))  float f32x4;
typedef __attribute__((ext_vector_type(16))) float f32x16;
typedef __attribute__((ext_vector_type(8)))  short bf16x8;       // 8 bf16 in 4 VGPRs
typedef __attribute__((ext_vector_type(4)))  unsigned int u32x4;

// float -> bf16 bits, round-to-nearest-even (finite inputs only)
static __device__ __forceinline__ unsigned short f2bf(float f) {
    unsigned int u = __float_as_uint(f);
    u = (u + 0x7FFFu + ((u >> 16) & 1u)) >> 16;
    return (unsigned short)u;
}
static __device__ __forceinline__ unsigned int pk2(float a, float b) {
    return (unsigned int)f2bf(a) | ((unsigned int)f2bf(b) << 16);
}

// ---------------------------------------------------------------------------
// K1: 2x2 average pool. x[b][c][128][128] -> xp[b][c][64*64]
// ---------------------------------------------------------------------------
__global__ __launch_bounds__(256) void pool_kernel(const float* __restrict__ x,
                                                   float* __restrict__ xp) {
    int tid = blockIdx.x * 256 + threadIdx.x;      // B*C*NP threads
    int wp = tid & 63;
    int hp = (tid >> 6) & 63;
    int bc = tid >> 12;
    const float* src = x + (size_t)bc * (HH * WW) + (2 * hp) * WW + 2 * wp;
    float2 a = *(const float2*)(src);
    float2 b = *(const float2*)(src + WW);
    xp[tid] = 0.25f * (a.x + a.y + b.x + b.y);
}

// ---------------------------------------------------------------------------
// K2: fused QKV projection GEMM (fp32 math), bf16 outputs in two layouts:
//   qk[b][n][64]  : o 0..31 = q, 32..63 = k   (token-major, for QK^T frags)
//   vt[b][c][n]   : c 0..255                  (channel-major, for PV A frags)
// ---------------------------------------------------------------------------
__global__ __launch_bounds__(256) void proj_kernel(const float* __restrict__ xp,
    const float* __restrict__ wq, const float* __restrict__ bq,
    const float* __restrict__ wk, const float* __restrict__ bk,
    const float* __restrict__ wv, const float* __restrict__ bv,
    unsigned short* __restrict__ qk, unsigned short* __restrict__ vt) {
    __shared__ float lx[32][64];    // [c][n]
    __shared__ float lwT[32][64];   // [c][o]
    int t = threadIdx.x;
    int ot = blockIdx.x % 5;
    int nt = (blockIdx.x / 5) & 63;
    int b  = blockIdx.x / 320;

    float acc[4][4];
    #pragma unroll
    for (int i = 0; i < 4; i++)
        #pragma unroll
        for (int j = 0; j < 4; j++) acc[i][j] = 0.f;

    int n0 = (t & 15) * 4;
    int o0 = (t >> 4) * 4;

    int o_l = t >> 2;               // 0..63 weight row
    int og  = ot * 64 + o_l;
    const float* wrow;
    if (og < 32)      wrow = wq + og * CC;
    else if (og < 64) wrow = wk + (og - 32) * CC;
    else              wrow = wv + (og - 64) * CC;
    int c8 = (t & 3) * 8;

    const float* xbase = xp + (size_t)b * CC * NP + nt * 64;
    int cl = t >> 3;                // 0..31
    int nl = (t & 7) * 8;

    for (int c0 = 0; c0 < 256; c0 += 32) {
        const float* xg = xbase + (size_t)(c0 + cl) * NP + nl;
        float4 v0 = *(const float4*)(xg);
        float4 v1 = *(const float4*)(xg + 4);
        float4 w0 = *(const float4*)(wrow + c0 + c8);
        float4 w1 = *(const float4*)(wrow + c0 + c8 + 4);
        __syncthreads();
        *(float4*)&lx[cl][nl]     = v0;
        *(float4*)&lx[cl][nl + 4] = v1;
        lwT[c8 + 0][o_l] = w0.x; lwT[c8 + 1][o_l] = w0.y;
        lwT[c8 + 2][o_l] = w0.z; lwT[c8 + 3][o_l] = w0.w;
        lwT[c8 + 4][o_l] = w1.x; lwT[c8 + 5][o_l] = w1.y;
        lwT[c8 + 6][o_l] = w1.z; lwT[c8 + 7][o_l] = w1.w;
        __syncthreads();
        #pragma unroll
        for (int cc = 0; cc < 32; cc += 4) {
            float4 xv[4], wv4[4];
            #pragma unroll
            for (int ci = 0; ci < 4; ci++) {
                xv[ci]  = *(const float4*)&lx[cc + ci][n0];
                wv4[ci] = *(const float4*)&lwT[cc + ci][o0];
            }
            #pragma unroll
            for (int ci = 0; ci < 4; ci++) {
                float xn[4] = {xv[ci].x, xv[ci].y, xv[ci].z, xv[ci].w};
                float wo[4] = {wv4[ci].x, wv4[ci].y, wv4[ci].z, wv4[ci].w};
                #pragma unroll
                for (int ni = 0; ni < 4; ni++)
                    #pragma unroll
                    for (int oi = 0; oi < 4; oi++)
                        acc[ni][oi] += xn[ni] * wo[oi];
            }
        }
    }

    float bias[4];
    #pragma unroll
    for (int oi = 0; oi < 4; oi++) {
        int o = ot * 64 + o0 + oi;
        bias[oi] = (o < 32) ? bq[o] : (o < 64) ? bk[o - 32] : bv[o - 64];
    }

    if (ot == 0) {
        #pragma unroll
        for (int ni = 0; ni < 4; ni++) {
            ushort4 r;
            r.x = f2bf(acc[ni][0] + bias[0]);
            r.y = f2bf(acc[ni][1] + bias[1]);
            r.z = f2bf(acc[ni][2] + bias[2]);
            r.w = f2bf(acc[ni][3] + bias[3]);
            int n = nt * 64 + n0 + ni;
            *(ushort4*)(qk + ((size_t)b * NP + n) * 64 + o0) = r;
        }
    } else {
        #pragma unroll
        for (int oi = 0; oi < 4; oi++) {
            int c = ot * 64 + o0 + oi - 64;
            ushort4 r;
            r.x = f2bf(acc[0][oi] + bias[oi]);
            r.y = f2bf(acc[1][oi] + bias[oi]);
            r.z = f2bf(acc[2][oi] + bias[oi]);
            r.w = f2bf(acc[3][oi] + bias[oi]);
            *(ushort4*)(vt + ((size_t)b * CC + c) * NP + nt * 64 + n0) = r;
        }
    }
}

// ---------------------------------------------------------------------------
// K3: swapped-operand 32x32 MFMA flash attention, split-K x4.
// Block j: batch b=j&3 (pins one batch per XCD), q-tile qt=j>>2 (32 q rows).
// Wave w owns keys [w*1024, (w+1)*1024) in 32-key chunks; exact combine at end.
//
// QK^T (swapped): S^T = mfma_32x32x16(A=K, B=Q) accumulated over 2 ch-halves.
//   D layout (m74/m101): col=lane&31 = q; row=(r&3)+8*(r>>2)+4*(lane>>5) = key.
//   -> lane (q,hi) holds P for 16 keys; softmax = 15 in-lane ops + 1 shfl_xor(32).
// PV: out[c][q] = mfma(A=V^T, B=P). A-frag: row=lane&31=c, k=(lane>>5)*8+e ->
//   16B contiguous load from vt[c][n]. B=P built in-register via pk2 + shfl_xor(32).
// ---------------------------------------------------------------------------
__global__ __launch_bounds__(256, 2) void flash32_kernel(const unsigned short* __restrict__ qk,
                                                         const unsigned short* __restrict__ vt,
                                                         float* __restrict__ att) {
    __shared__ float cacc[64][136];   // combine: one wave's 128 acc f32 per lane (16B-aligned rows)
    __shared__ float cml[64][2];      // combine: m, l per lane
    int t    = threadIdx.x;
    int lane = t & 63;
    int w    = t >> 6;
    int j    = blockIdx.x;
    int b    = j & 3;                 // batch -> XCD pinning
    int qt   = j >> 2;                // 0..127 q-tile (32 rows)

    const unsigned short* qkb = qk + (size_t)b * NP * 64;
    const unsigned short* vtb = vt + (size_t)b * CC * NP;

    int q  = lane & 31;
    int hi = lane >> 5;

    // Q B-frags: col=q, k=hi*8+e (ch 0-15) and +16 (ch 16-31); held whole kernel
    const unsigned short* qrow = qkb + (size_t)(qt * 32 + q) * 64;
    bf16x8 qf0 = *(const bf16x8*)(qrow + hi * 8);
    bf16x8 qf1 = *(const bf16x8*)(qrow + 16 + hi * 8);

    f32x16 acc[8];
    #pragma unroll
    for (int ct = 0; ct < 8; ct++)
        #pragma unroll
        for (int r = 0; r < 16; r++) acc[ct][r] = 0.f;
    float mrun = -3.0e38f, lrun = 0.f;

    const f32x16 z16 = {0.f,0.f,0.f,0.f,0.f,0.f,0.f,0.f,0.f,0.f,0.f,0.f,0.f,0.f,0.f,0.f};

    for (int kci = 0; kci < 32; ++kci) {
        int kbase = (w * 32 + kci) * 32;

        // ---- QK^T swapped: A=K (row=key), B=Q -> S^T
        const unsigned short* krow = qkb + (size_t)(kbase + q) * 64 + 32;
        bf16x8 kf0 = *(const bf16x8*)(krow + hi * 8);
        bf16x8 kf1 = *(const bf16x8*)(krow + 16 + hi * 8);
        f32x16 s = __builtin_amdgcn_mfma_f32_32x32x16_bf16(kf0, qf0, z16, 0, 0, 0);
        s = __builtin_amdgcn_mfma_f32_32x32x16_bf16(kf1, qf1, s, 0, 0, 0);

        // ---- in-lane max over 16 keys + 1 cross-half swap
        float m01 = fmaxf(s[0], s[1]),   m23 = fmaxf(s[2], s[3]);
        float m45 = fmaxf(s[4], s[5]),   m67 = fmaxf(s[6], s[7]);
        float m89 = fmaxf(s[8], s[9]),   mab = fmaxf(s[10], s[11]);
        float mcd = fmaxf(s[12], s[13]), mef = fmaxf(s[14], s[15]);
        float mx = fmaxf(fmaxf(fmaxf(m01, m23), fmaxf(m45, m67)),
                         fmaxf(fmaxf(m89, mab), fmaxf(mcd, mef)));
        mx = fmaxf(mx, __shfl_xor(mx, 32, 64));

        // ---- defer-max (T13): rescale only when max grew by > 8
        if (!__all(mx - mrun <= 8.0f)) {
            float mn = fmaxf(mrun, mx);
            float sc = __expf(mrun - mn);
            mrun = mn;
            lrun *= sc;
            #pragma unroll
            for (int ct = 0; ct < 8; ct++)
                #pragma unroll
                for (int r = 0; r < 16; r++) acc[ct][r] *= sc;
        }

        // ---- P = exp(S^T - m) in-lane; sum in-lane + 1 swap
        float p[16];
        #pragma unroll
        for (int r = 0; r < 16; r++) p[r] = __expf(s[r] - mrun);
        float ss = 0.f;
        #pragma unroll
        for (int r = 0; r < 16; r++) ss += p[r];
        ss += __shfl_xor(ss, 32, 64);
        lrun += ss;

        // ---- PV: per 16-key window, build P B-frag in-register, 8 c-tiles
        #pragma unroll
        for (int w2 = 0; w2 < 2; w2++) {
            unsigned int a0 = pk2(p[8 * w2 + 0], p[8 * w2 + 1]);
            unsigned int a1 = pk2(p[8 * w2 + 2], p[8 * w2 + 3]);
            unsigned int c0 = pk2(p[8 * w2 + 4], p[8 * w2 + 5]);
            unsigned int c1 = pk2(p[8 * w2 + 6], p[8 * w2 + 7]);
            unsigned int sa0 = __shfl_xor(a0, 32, 64);
            unsigned int sa1 = __shfl_xor(a1, 32, 64);
            unsigned int sc0 = __shfl_xor(c0, 32, 64);
            unsigned int sc1 = __shfl_xor(c1, 32, 64);
            u32x4 fr;
            if (hi == 0) { fr[0] = a0;  fr[1] = a1;  fr[2] = sa0; fr[3] = sa1; }
            else         { fr[0] = sc0; fr[1] = sc1; fr[2] = c0;  fr[3] = c1;  }
            bf16x8 pf = __builtin_bit_cast(bf16x8, fr);
            const unsigned short* vb = vtb + kbase + w2 * 16 + hi * 8;
            #pragma unroll
            for (int ct = 0; ct < 8; ct++) {
                bf16x8 vf = *(const bf16x8*)(vb + (size_t)(ct * 32 + q) * NP);
                acc[ct] = __builtin_amdgcn_mfma_f32_32x32x16_bf16(vf, pf, acc[ct], 0, 0, 0);
            }
        }
    }

    // ---- split-K combine: waves 3,2,1 hand state to wave 0 (elementwise per lane)
    for (int sIdx = 3; sIdx >= 1; --sIdx) {
        if (w == sIdx) {
            #pragma unroll
            for (int ct = 0; ct < 8; ct++)
                #pragma unroll
                for (int rr = 0; rr < 4; rr++) {
                    float4 v4 = {acc[ct][rr*4+0], acc[ct][rr*4+1], acc[ct][rr*4+2], acc[ct][rr*4+3]};
                    *(float4*)&cacc[lane][ct * 16 + rr * 4] = v4;
                }
            cml[lane][0] = mrun; cml[lane][1] = lrun;
        }
        __syncthreads();
        if (w == 0) {
            float mo = cml[lane][0];
            float lo = cml[lane][1];
            float mn = fmaxf(mrun, mo);
            float e0 = __expf(mrun - mn);
            float e1 = __expf(mo - mn);
            mrun = mn;
            lrun = lrun * e0 + lo * e1;
            #pragma unroll
            for (int ct = 0; ct < 8; ct++)
                #pragma unroll
                for (int r = 0; r < 16; r++)
                    acc[ct][r] = acc[ct][r] * e0 + cacc[lane][ct * 16 + r] * e1;
        }
        __syncthreads();
    }

    if (w == 0) {
        float inv = 1.0f / lrun;
        #pragma unroll
        for (int ct = 0; ct < 8; ct++)
            #pragma unroll
            for (int r = 0; r < 16; r++) {
                int c = ct * 32 + (r & 3) + 8 * (r >> 2) + 4 * hi;
                att[((size_t)b * CC + c) * NP + qt * 32 + q] = acc[ct][r] * inv;
            }
    }
}

// ---------------------------------------------------------------------------
// K4: bilinear x2 upsample (half-pixel, edge clamp) + gamma * up + x
// ---------------------------------------------------------------------------
__global__ __launch_bounds__(256) void upsample_kernel(const float* __restrict__ att,
                                                       const float* __restrict__ x,
                                                       const float* __restrict__ gamma,
                                                       float* __restrict__ out) {
    int tid = blockIdx.x * 256 + threadIdx.x;    // B*C*H*W
    int w = tid & 127;
    int h = (tid >> 7) & 127;
    int bc = tid >> 14;
    float g = gamma[0];
    float sh = 0.5f * h - 0.25f;
    float sw = 0.5f * w - 0.25f;
    float fhf = floorf(sh), fwf = floorf(sw);
    float th = sh - fhf, tw = sw - fwf;
    int ih = (int)fhf, iw = (int)fwf;
    int ih0 = ih < 0 ? 0 : ih;
    int ih1 = ih + 1 > 63 ? 63 : ih + 1;
    int iw0 = iw < 0 ? 0 : iw;
    int iw1 = iw + 1 > 63 ? 63 : iw + 1;
    const float* a = att + (size_t)bc * NP;
    float v00 = a[ih0 * 64 + iw0], v01 = a[ih0 * 64 + iw1];
    float v10 = a[ih1 * 64 + iw0], v11 = a[ih1 * 64 + iw1];
    float top = v00 + tw * (v01 - v00);
    float bot = v10 + tw * (v11 - v10);
    float up  = top + th * (bot - top);
    out[tid] = g * up + x[tid];
}

// ---------------------------------------------------------------------------
extern "C" void kernel_launch(void* const* d_in, const int* in_sizes, int n_in,
                              void* d_out, int out_size, void* d_ws, size_t ws_size,
                              hipStream_t stream) {
    (void)in_sizes; (void)n_in; (void)out_size; (void)ws_size;
    const float* x     = (const float*)d_in[0];
    const float* wq    = (const float*)d_in[1];
    const float* bq    = (const float*)d_in[2];
    const float* wk    = (const float*)d_in[3];
    const float* bk    = (const float*)d_in[4];
    const float* wv    = (const float*)d_in[5];
    const float* bv    = (const float*)d_in[6];
    const float* gamma = (const float*)d_in[7];
    float* out = (float*)d_out;
    float* ws  = (float*)d_ws;

    float*          xp  = ws;                                  // 4,194,304 f32 (16 MB)
    unsigned short* qkb = (unsigned short*)(ws + 4194304);     // 4*4096*64  bf16 (2 MB)
    unsigned short* vtb = qkb + 1048576;                       // 4*256*4096 bf16 (8 MB)
    float*          att = (float*)(vtb + 4194304);             // 4,194,304 f32 (16 MB)

    pool_kernel<<<16384, 256, 0, stream>>>(x, xp);
    proj_kernel<<<1280, 256, 0, stream>>>(xp, wq, bq, wk, bk, wv, bv, qkb, vtb);
    flash32_kernel<<<512, 256, 0, stream>>>(qkb, vtb, att);
    upsample_kernel<<<65536, 256, 0, stream>>>(att, x, gamma, out);
}